// Round 1
// baseline (52.053 us; speedup 1.0000x reference)
//
#include <hip/hip_runtime.h>

// NodeCycleFeatures: B=2048 graphs, N=64 nodes, A = E[...,1] symmetric 0/1, zero diag.
// One wave (64 lanes) per batch. Lane i owns row i as a 64-bit mask.
// k2 = A^2 via popcount(row_i & row_k); k3 row sums via bit-scan over rows[j].
// All needed quantities reduce to per-lane partials + one wave reduction.

constexpr int BATCH = 2048;
constexpr int NN = 64;

__global__ __launch_bounds__(64) void node_cycle_kernel(
    const float2* __restrict__ E2,   // [B,N,N] of (1-A, A)
    const float* __restrict__ nmask, // [B,N]
    float* __restrict__ out)         // x: [B,N,3] then y: [B,4]
{
  const int b = blockIdx.x;
  const int lane = threadIdx.x;

  __shared__ unsigned long long rows[NN];
  __shared__ unsigned char k2s[NN][NN + 1]; // stride 65 -> 2-way bank aliasing (free)
  __shared__ float dsh[NN];
  __shared__ float c3sh[NN];

  const float2* __restrict__ Eb = E2 + (size_t)b * NN * NN;

  // ---- Phase 1: build adjacency row masks via ballot (row i from iter i) ----
  unsigned long long myrow = 0ull;
  #pragma unroll 8
  for (int i = 0; i < NN; ++i) {
    float v = Eb[i * NN + lane].y;             // A[b, i, lane]
    unsigned long long m = __ballot(v > 0.5f);
    if (lane == i) { rows[i] = m; myrow = m; }
  }
  __syncthreads();

  const float di = (float)__popcll(myrow);     // degree of node `lane`
  dsh[lane] = di;

  // ---- Phase 2: k2 row + on-the-fly diag4, c3, t3 partials ----
  float diag4 = 0.f, c3 = 0.f, t3p = 0.f;
  #pragma unroll 4
  for (int k = 0; k < NN; ++k) {
    unsigned long long rk = rows[k];           // uniform -> broadcast read
    int p = __popcll(myrow & rk);              // k2[lane][k]
    k2s[lane][k] = (unsigned char)p;
    float k2v = (float)p;
    float k2sq = k2v * k2v;
    diag4 += k2sq;                             // diag(A^4)[lane]
    if ((myrow >> k) & 1ull) { c3 += k2v; t3p += k2sq; }  // diag(A^3), sum A*k2^2
  }
  c3sh[lane] = c3;
  __syncthreads();

  // ---- Phase 3: k3 row (never stored) + t1, t8, diag5 partials ----
  float t1p = 0.f, t8p = 0.f, diag5 = 0.f;
  for (int j = 0; j < NN; ++j) {
    unsigned long long rj = rows[j];           // uniform across lanes
    int s = 0;
    while (rj) {                               // uniform trip count: no divergence
      int k = __builtin_ctzll(rj);
      rj &= rj - 1ull;
      s += (int)k2s[lane][k];                  // k3[lane][j] accumulation
    }
    float sf = (float)s;
    t1p  += sf * sf;                           // -> trace(k6)
    t8p  += sf;                                // -> sum(k3)
    diag5 += (float)k2s[lane][j] * sf;         // -> diag(A^5)[lane]
  }

  // ---- Phase 4: A@d and A@c3 for c4/c5 ----
  float Ad = 0.f, Atri = 0.f;
  #pragma unroll 8
  for (int j = 0; j < NN; ++j) {
    float dj = dsh[j];
    float cj = c3sh[j];
    if ((myrow >> j) & 1ull) { Ad += dj; Atri += cj; }
  }

  // ---- Per-lane node quantities ----
  float c4 = diag4 - di * (di - 1.f) - Ad;
  float c5 = diag5 - 2.f * c3 * di - Atri + c3;
  // c6 trace-formula folded into one per-lane partial:
  // t1 -3t2 +9t3 -6t4 +6t5 -4t6 +4t7 +3t8 -12t9 +4t10
  float c6p = t1p
            - 3.f * (c3 * c3)
            + 9.f * t3p
            - 6.f * (di * diag4)
            + 6.f * diag4
            - 4.f * c3
            + 4.f * (di * di * di)
            + 3.f * t8p
            - 12.f * (di * di)
            + 4.f * di;

  // ---- Wave reduction of the four batch sums ----
  float sc3 = c3, sc4 = c4, sc5 = c5, sc6 = c6p;
  #pragma unroll
  for (int off = 32; off > 0; off >>= 1) {
    sc3 += __shfl_xor(sc3, off);
    sc4 += __shfl_xor(sc4, off);
    sc5 += __shfl_xor(sc5, off);
    sc6 += __shfl_xor(sc6, off);
  }

  // ---- Outputs ----
  float m = nmask[b * NN + lane];
  float x0 = fminf(c3 * 0.5f * m * 0.1f, 1.f);
  float x1 = fminf(c4 * 0.5f * m * 0.1f, 1.f);
  float x2 = fminf(c5 * 0.5f * m * 0.1f, 1.f);
  float* xo = out + ((size_t)b * NN + lane) * 3;
  xo[0] = x0; xo[1] = x1; xo[2] = x2;

  if (lane == 0) {
    float4 y;
    y.x = fminf(sc3 * (1.f / 6.f)  * 0.1f, 1.f);
    y.y = fminf(sc4 * (1.f / 8.f)  * 0.1f, 1.f);
    y.z = fminf(sc5 * (1.f / 10.f) * 0.1f, 1.f);
    y.w = fminf(sc6 * (1.f / 12.f) * 0.1f, 1.f);
    *reinterpret_cast<float4*>(out + (size_t)BATCH * NN * 3 + b * 4) = y;
  }
}

extern "C" void kernel_launch(void* const* d_in, const int* in_sizes, int n_in,
                              void* d_out, int out_size, void* d_ws, size_t ws_size,
                              hipStream_t stream) {
  const float2* E2 = reinterpret_cast<const float2*>(d_in[0]);
  const float* nmask = reinterpret_cast<const float*>(d_in[1]);
  float* out = reinterpret_cast<float*>(d_out);
  node_cycle_kernel<<<BATCH, NN, 0, stream>>>(E2, nmask, out);
}

// Round 2
// 35.058 us; speedup vs baseline: 1.4848x; 1.4848x over previous
//
#include <hip/hip_runtime.h>

// NodeCycleFeatures: B=2048 graphs, N=64, A = E[...,1] symmetric 0/1, zero diag.
// One wave per batch. Lane i owns row i as a 64-bit mask.
// k2[i][k] = popcount(row_i & row_k)  (<= 63, exact)
// k2 row kept as 6 bit-planes in registers ->
// k3[i][j] = sum_t 2^t * popcount(plane_t[i] & row_j)  (pure VALU, no LDS bytes)
// Everything reduces to per-lane partials + one wave reduction.

constexpr int BATCH = 2048;
constexpr int NN = 64;

__global__ __launch_bounds__(64) void node_cycle_kernel(
    const float4* __restrict__ E4,   // [B,N,N,2] floats viewed as float4
    const float* __restrict__ nmask, // [B,N]
    float* __restrict__ out)         // x: [B,N,3] then y: [B,4]
{
  const int b = blockIdx.x;
  const int lane = threadIdx.x;

  __shared__ unsigned long long rows[NN];
  __shared__ float c3sh[NN];

  const float4* __restrict__ Eb = E4 + (size_t)b * (NN * NN / 2);

  // ---- Phase 1: build row masks from coalesced float4 loads (A symmetric:
  // row c == column c). float4 #(t*64+lane) holds A-row (2t + (lane>=32)),
  // cols 2*(lane&31), 2*(lane&31)+1 in .y/.w. Lane accumulates the two
  // column-masks over its row-parity; shfl_xor(32) merges parities.
  unsigned long long mA = 0ull, mB = 0ull;
  const int rbase = (lane >= 32) ? 1 : 0;
  #pragma unroll
  for (int t = 0; t < 32; ++t) {
    float4 f = Eb[t * 64 + lane];
    const int bitpos = 2 * t + rbase;
    mA |= (unsigned long long)(f.y > 0.5f) << bitpos;
    mB |= (unsigned long long)(f.w > 0.5f) << bitpos;
  }
  mA |= __shfl_xor(mA, 32);
  mB |= __shfl_xor(mB, 32);
  if (lane < 32) {
    const int rpair = lane * 2;
    rows[rpair] = mA;
    rows[rpair + 1] = mB;
  }
  __syncthreads();

  const unsigned long long myrow = rows[lane];
  const float di = (float)__popcll(myrow); // degree

  // ---- Phase 2: k2 row -> 6 bit-planes; diag4, c3, t3 partials ----
  unsigned long long pl0 = 0, pl1 = 0, pl2 = 0, pl3 = 0, pl4 = 0, pl5 = 0;
  float diag4 = 0.f, c3 = 0.f, t3p = 0.f;
  #pragma unroll
  for (int k = 0; k < NN; ++k) {
    const unsigned long long rk = rows[k];          // uniform broadcast
    const unsigned int p = (unsigned int)__popcll(myrow & rk); // k2[lane][k]
    pl0 |= (unsigned long long)(p & 1u) << k;
    pl1 |= (unsigned long long)((p >> 1) & 1u) << k;
    pl2 |= (unsigned long long)((p >> 2) & 1u) << k;
    pl3 |= (unsigned long long)((p >> 3) & 1u) << k;
    pl4 |= (unsigned long long)((p >> 4) & 1u) << k;
    pl5 |= (unsigned long long)((p >> 5) & 1u) << k;
    const float pf = (float)p;
    diag4 += pf * pf;                               // diag(A^4)
    if ((myrow >> k) & 1ull) { c3 += pf; t3p += pf * pf; }
  }
  c3sh[lane] = c3;
  __syncthreads();

  // ---- Phase 3: k3 row via bit-plane popcounts; t1, t8, diag5, A@d, A@c3 ----
  float t1p = 0.f, t8p = 0.f, diag5 = 0.f, Ad = 0.f, Atri = 0.f;
  #pragma unroll
  for (int j = 0; j < NN; ++j) {
    const unsigned long long rj = rows[j];          // uniform broadcast
    const unsigned int s =
          (unsigned int)__popcll(pl0 & rj)
        + ((unsigned int)__popcll(pl1 & rj) << 1)
        + ((unsigned int)__popcll(pl2 & rj) << 2)
        + ((unsigned int)__popcll(pl3 & rj) << 3)
        + ((unsigned int)__popcll(pl4 & rj) << 4)
        + ((unsigned int)__popcll(pl5 & rj) << 5);  // k3[lane][j]
    const unsigned int pj = (unsigned int)__popcll(myrow & rj); // k2[lane][j]
    const float sf = (float)s;
    t1p += sf * sf;                                 // -> trace(k6)
    t8p += sf;                                      // -> sum(k3)
    diag5 += (float)pj * sf;                        // diag(A^5)
    if ((myrow >> j) & 1ull) {
      Ad += (float)__popcll(rj);                    // (A@d)[lane]
      Atri += c3sh[j];                              // (A@c3)[lane]
    }
  }

  // ---- Per-lane node quantities ----
  const float c4 = diag4 - di * (di - 1.f) - Ad;
  const float c5 = diag5 - 2.f * c3 * di - Atri + c3;
  // c6 = t1 -3t2 +9t3 -6t4 +6t5 -4t6 +4t7 +3t8 -12t9 +4t10, all per-lane foldable
  const float c6p = t1p
            - 3.f * (c3 * c3)
            + 9.f * t3p
            - 6.f * (di * diag4)
            + 6.f * diag4
            - 4.f * c3
            + 4.f * (di * di * di)
            + 3.f * t8p
            - 12.f * (di * di)
            + 4.f * di;

  // ---- Wave reduction of the four batch sums ----
  float sc3 = c3, sc4 = c4, sc5 = c5, sc6 = c6p;
  #pragma unroll
  for (int off = 32; off > 0; off >>= 1) {
    sc3 += __shfl_xor(sc3, off);
    sc4 += __shfl_xor(sc4, off);
    sc5 += __shfl_xor(sc5, off);
    sc6 += __shfl_xor(sc6, off);
  }

  // ---- Outputs ----
  const float m = nmask[b * NN + lane];
  float* xo = out + ((size_t)b * NN + lane) * 3;
  xo[0] = fminf(c3 * 0.5f * m * 0.1f, 1.f);
  xo[1] = fminf(c4 * 0.5f * m * 0.1f, 1.f);
  xo[2] = fminf(c5 * 0.5f * m * 0.1f, 1.f);

  if (lane == 0) {
    float4 y;
    y.x = fminf(sc3 * (1.f / 6.f)  * 0.1f, 1.f);
    y.y = fminf(sc4 * (1.f / 8.f)  * 0.1f, 1.f);
    y.z = fminf(sc5 * (1.f / 10.f) * 0.1f, 1.f);
    y.w = fminf(sc6 * (1.f / 12.f) * 0.1f, 1.f);
    *reinterpret_cast<float4*>(out + (size_t)BATCH * NN * 3 + b * 4) = y;
  }
}

extern "C" void kernel_launch(void* const* d_in, const int* in_sizes, int n_in,
                              void* d_out, int out_size, void* d_ws, size_t ws_size,
                              hipStream_t stream) {
  const float4* E4 = reinterpret_cast<const float4*>(d_in[0]);
  const float* nmask = reinterpret_cast<const float*>(d_in[1]);
  float* out = reinterpret_cast<float*>(d_out);
  node_cycle_kernel<<<BATCH, NN, 0, stream>>>(E4, nmask, out);
}

// Round 3
// 28.683 us; speedup vs baseline: 1.8147x; 1.2222x over previous
//
#include <hip/hip_runtime.h>

// NodeCycleFeatures: B=2048 graphs, N=64, A = E[...,1] symmetric 0/1, zero diag.
// 4 waves per batch (256-thread block). Lane i owns row i; wave w owns the
// k/j-subrange [16w, 16w+16) of the O(N^2) popcount loops. Partials merged
// via LDS. k2 row kept as 6 bit-planes (2x u32 halves); k3[i][j] recovered as
// sum_t 2^t * popcount(plane_t & row_j). All integer-exact in fp32.

constexpr int BATCH = 2048;
constexpr int NN = 64;

union UF { unsigned int u; float f; };

__global__ __launch_bounds__(256, 8) void node_cycle_kernel(
    const float2* __restrict__ E2,   // [B,N,N] of (1-A, A)
    const float* __restrict__ nmask, // [B,N]
    float* __restrict__ out)         // x: [B,N,3] then y: [B,4]
{
  const int b = blockIdx.x;
  const int tid = threadIdx.x;
  const int lane = tid & 63;
  const int w = tid >> 6;            // wave id 0..3
  const int k0 = w * 16;             // this wave's k/j subrange base

  __shared__ uint4 jinfo[NN];                  // {row_lo, row_hi, deg_f, c3_f}
  __shared__ unsigned int ppart[4][6][NN];     // partial bit-planes (16 bits each)
  __shared__ float c3part[4][NN];
  __shared__ float acc[4][7][NN];              // per-wave partials

  const float2* __restrict__ Eb = E2 + (size_t)b * (NN * NN);

  // ---- Phase 1: wave w ballots rows [16w, 16w+16) ----
  #pragma unroll
  for (int i = 0; i < 16; ++i) {
    const int r = k0 + i;
    const float v = Eb[r * NN + lane].y;       // A[b, r, lane]
    const unsigned long long m = __ballot(v > 0.5f);
    if (lane == 0) {
      jinfo[r].x = (unsigned)m;
      jinfo[r].y = (unsigned)(m >> 32);
    }
  }
  __syncthreads();

  const unsigned mlo = jinfo[lane].x;
  const unsigned mhi = jinfo[lane].y;
  if (w == 0) {                                 // stash degree as float
    UF d; d.f = (float)(__popc(mlo) + __popc(mhi));
    jinfo[lane].z = d.u;
  }

  const unsigned selrow = (k0 & 32) ? mhi : mlo; // half of myrow holding bits k0..k0+15
  const int shbase = k0 & 31;

  // ---- Phase 2: k2[lane][k] for k in subrange; partial planes + partials ----
  unsigned pp0=0,pp1=0,pp2=0,pp3=0,pp4=0,pp5=0;
  unsigned pk[4] = {0u,0u,0u,0u};              // packed k2 bytes for phase 3
  float diag4 = 0.f, c3 = 0.f, t3p = 0.f;
  #pragma unroll
  for (int q = 0; q < 16; ++q) {
    const int k = k0 + q;
    const uint4 ji = jinfo[k];                 // uniform broadcast b128
    const unsigned p = (unsigned)__popc(ji.x & mlo) + (unsigned)__popc(ji.y & mhi);
    pp0 |= ((p      ) & 1u) << q;
    pp1 |= ((p >> 1) & 1u) << q;
    pp2 |= ((p >> 2) & 1u) << q;
    pp3 |= ((p >> 3) & 1u) << q;
    pp4 |= ((p >> 4) & 1u) << q;
    pp5 |= ((p >> 5) & 1u) << q;
    pk[q >> 2] |= p << (8 * (q & 3));          // static index under full unroll
    const float pf = (float)p;
    diag4 = fmaf(pf, pf, diag4);
    const unsigned bit = (selrow >> (shbase + q)) & 1u;
    const float selpf = bit ? pf : 0.f;
    c3 += selpf;
    t3p = fmaf(selpf, pf, t3p);
  }
  ppart[w][0][lane]=pp0; ppart[w][1][lane]=pp1; ppart[w][2][lane]=pp2;
  ppart[w][3][lane]=pp3; ppart[w][4][lane]=pp4; ppart[w][5][lane]=pp5;
  c3part[w][lane] = c3;
  acc[w][0][lane] = diag4;
  acc[w][1][lane] = t3p;
  __syncthreads();

  // ---- Merge: full bit-planes (as u32 halves) + full c3 per row ----
  unsigned pl_lo[6], pl_hi[6];
  #pragma unroll
  for (int t = 0; t < 6; ++t) {
    pl_lo[t] = ppart[0][t][lane] | (ppart[1][t][lane] << 16);
    pl_hi[t] = ppart[2][t][lane] | (ppart[3][t][lane] << 16);
  }
  const float c3full = c3part[0][lane] + c3part[1][lane]
                     + c3part[2][lane] + c3part[3][lane];
  if (w == 0) { UF u; u.f = c3full; jinfo[lane].w = u.u; }
  __syncthreads();

  // ---- Phase 3: k3[lane][j] for j in subrange via bit-plane popcounts ----
  float t1p=0.f, t8p=0.f, diag5=0.f, Ad=0.f, Atri=0.f;
  #pragma unroll
  for (int q = 0; q < 16; ++q) {
    const int j = k0 + q;
    const uint4 ji = jinfo[j];                 // uniform broadcast b128
    const unsigned s =
          ((unsigned)__popc(pl_lo[0] & ji.x) + (unsigned)__popc(pl_hi[0] & ji.y))
        + (((unsigned)__popc(pl_lo[1] & ji.x) + (unsigned)__popc(pl_hi[1] & ji.y)) << 1)
        + (((unsigned)__popc(pl_lo[2] & ji.x) + (unsigned)__popc(pl_hi[2] & ji.y)) << 2)
        + (((unsigned)__popc(pl_lo[3] & ji.x) + (unsigned)__popc(pl_hi[3] & ji.y)) << 3)
        + (((unsigned)__popc(pl_lo[4] & ji.x) + (unsigned)__popc(pl_hi[4] & ji.y)) << 4)
        + (((unsigned)__popc(pl_lo[5] & ji.x) + (unsigned)__popc(pl_hi[5] & ji.y)) << 5);
    const unsigned pj = (pk[q >> 2] >> (8 * (q & 3))) & 0xffu; // k2[lane][j]
    const float sf = (float)s;
    UF dj; dj.u = ji.z;
    UF cj; cj.u = ji.w;
    t1p = fmaf(sf, sf, t1p);                   // -> trace(k6)
    t8p += sf;                                 // -> sum(k3)
    diag5 = fmaf((float)pj, sf, diag5);        // -> diag(A^5)
    const unsigned bit = (selrow >> (shbase + q)) & 1u;
    Ad  += bit ? dj.f : 0.f;                   // -> (A@d)[lane]
    Atri += bit ? cj.f : 0.f;                  // -> (A@c3)[lane]
  }
  acc[w][2][lane]=t1p; acc[w][3][lane]=t8p; acc[w][4][lane]=diag5;
  acc[w][5][lane]=Ad;  acc[w][6][lane]=Atri;
  __syncthreads();

  // ---- Final: wave 0 merges partials, computes node/graph quantities ----
  if (w == 0) {
    float f[7];
    #pragma unroll
    for (int q2 = 0; q2 < 7; ++q2)
      f[q2] = acc[0][q2][lane] + acc[1][q2][lane] + acc[2][q2][lane] + acc[3][q2][lane];
    const float diag4F=f[0], t3F=f[1], t1F=f[2], t8F=f[3], d5F=f[4], AdF=f[5], AtF=f[6];
    const float di = (float)(__popc(mlo) + __popc(mhi));
    const float c3f = c3full;

    const float c4 = diag4F - di * (di - 1.f) - AdF;
    const float c5 = d5F - 2.f * c3f * di - AtF + c3f;
    const float c6p = t1F
              - 3.f * (c3f * c3f)
              + 9.f * t3F
              - 6.f * (di * diag4F)
              + 6.f * diag4F
              - 4.f * c3f
              + 4.f * (di * di * di)
              + 3.f * t8F
              - 12.f * (di * di)
              + 4.f * di;

    float sc3 = c3f, sc4 = c4, sc5 = c5, sc6 = c6p;
    #pragma unroll
    for (int off = 32; off > 0; off >>= 1) {
      sc3 += __shfl_xor(sc3, off);
      sc4 += __shfl_xor(sc4, off);
      sc5 += __shfl_xor(sc5, off);
      sc6 += __shfl_xor(sc6, off);
    }

    const float m = nmask[b * NN + lane];
    float* xo = out + ((size_t)b * NN + lane) * 3;
    xo[0] = fminf(c3f * 0.5f * m * 0.1f, 1.f);
    xo[1] = fminf(c4 * 0.5f * m * 0.1f, 1.f);
    xo[2] = fminf(c5 * 0.5f * m * 0.1f, 1.f);

    if (lane == 0) {
      float4 y;
      y.x = fminf(sc3 * (1.f / 6.f)  * 0.1f, 1.f);
      y.y = fminf(sc4 * (1.f / 8.f)  * 0.1f, 1.f);
      y.z = fminf(sc5 * (1.f / 10.f) * 0.1f, 1.f);
      y.w = fminf(sc6 * (1.f / 12.f) * 0.1f, 1.f);
      *reinterpret_cast<float4*>(out + (size_t)BATCH * NN * 3 + b * 4) = y;
    }
  }
}

extern "C" void kernel_launch(void* const* d_in, const int* in_sizes, int n_in,
                              void* d_out, int out_size, void* d_ws, size_t ws_size,
                              hipStream_t stream) {
  const float2* E2 = reinterpret_cast<const float2*>(d_in[0]);
  const float* nmask = reinterpret_cast<const float*>(d_in[1]);
  float* out = reinterpret_cast<float*>(d_out);
  node_cycle_kernel<<<BATCH, 256, 0, stream>>>(E2, nmask, out);
}